// Round 4
// baseline (1778.587 us; speedup 1.0000x reference)
//
#include <hip/hip_runtime.h>

// TKMDAttention on MI355X — round 4: pure fp32 pipeline (inputs ARE float32 —
// proven by round-3 device-side dtype detection). No bf16 anywhere.
// Shapes: b=2, C=384, H=W=128, heads=8, ch=48, crop=8, N=64.
// windowstoimg mapping: token n of window (wy,wx) -> y = wy*8+(wx>>1), x = (wx&1)*64+n.
// top-k keep rule (tie-exact): keep i for k iff count(a_j > a_i) < k.
// Memory plan: d_out[b] region doubles as conv1-scratch (At) and pre-proj sum
// (Cbuf); proj writes into dead Bq region, then copy back. ws peak 75.6 MB.

#define HW 16384
#define CDIM 384
#define NHEADS 8
#define CH 48

// ---------------- zero ----------------
__global__ void zero_f32(float* p, int n) {
  int i = blockIdx.x * 256 + threadIdx.x;
  if (i < n) p[i] = 0.f;
}

// ---------------- copy ----------------
__global__ __launch_bounds__(256) void copy_f32(const float* __restrict__ src,
                                                float* __restrict__ dst, int n4) {
  int i = blockIdx.x * 256 + threadIdx.x;
  if (i < n4) reinterpret_cast<float4*>(dst)[i] = reinterpret_cast<const float4*>(src)[i];
}

// ---- 1x1 conv as GEMM: Out[oc,p] = sum_ic W[oc,ic]*X[ic,p] (single batch) ----
__global__ __launch_bounds__(256) void gemm1x1_f32(const float* __restrict__ Wt,
                                                   const float* __restrict__ X,
                                                   float* __restrict__ Out, int K) {
  __shared__ __align__(16) float Xs[16][68];  // 68 floats = 272 B, 16B-aligned rows
  __shared__ __align__(16) float Ws[16][68];
  const int tid = threadIdx.x;
  const int tx = tid & 15, ty = tid >> 4;
  const int p0 = blockIdx.x * 64;
  const int oc0 = blockIdx.y * 64;
  float acc[4][4] = {};
  for (int k0 = 0; k0 < K; k0 += 16) {
    {  // X tile: 16 rows x 64 cols, float4 per thread
      const int kk = tid >> 4, p4 = (tid & 15) * 4;
      *reinterpret_cast<float4*>(&Xs[kk][p4]) =
          *reinterpret_cast<const float4*>(&X[(size_t)(k0 + kk) * HW + p0 + p4]);
    }
    for (int s = tid; s < 1024; s += 256) {  // W tile (transposed into [k][oc])
      int ocl = s >> 4, kk = s & 15;
      Ws[kk][ocl] = Wt[(size_t)(oc0 + ocl) * K + k0 + kk];
    }
    __syncthreads();
#pragma unroll
    for (int kk = 0; kk < 16; kk++) {
      const float4 xv = *reinterpret_cast<const float4*>(&Xs[kk][tx * 4]);
      const float4 wv = *reinterpret_cast<const float4*>(&Ws[kk][ty * 4]);
      float xr[4] = {xv.x, xv.y, xv.z, xv.w};
      float wr[4] = {wv.x, wv.y, wv.z, wv.w};
#pragma unroll
      for (int i = 0; i < 4; i++)
#pragma unroll
        for (int j = 0; j < 4; j++) acc[i][j] += wr[i] * xr[j];
    }
    __syncthreads();
  }
#pragma unroll
  for (int i = 0; i < 4; i++) {
    const size_t base = (size_t)(oc0 + ty * 4 + i) * HW + p0 + tx * 4;
#pragma unroll
    for (int j = 0; j < 4; j++) Out[base + j] = acc[i][j];
  }
}

// ---- depthwise 3x3 pad1, 384 channels (one qkv third) ----
__global__ __launch_bounds__(256) void dwconv3(const float* __restrict__ A,
                                               const float* __restrict__ wdw,
                                               float* __restrict__ Bq) {
  const int idx = blockIdx.x * 256 + threadIdx.x;  // flat over (ch<384, y, x)
  const int x = idx & 127;
  const int y = (idx >> 7) & 127;
  const int ch = idx >> 14;
  float w[9];
#pragma unroll
  for (int t = 0; t < 9; t++) w[t] = wdw[ch * 9 + t];
  const float* Ap = A + (size_t)ch * HW;
  float acc = 0.f;
#pragma unroll
  for (int ky = 0; ky < 3; ky++) {
    const int yy = y + ky - 1;
    if (yy < 0 || yy > 127) continue;
#pragma unroll
    for (int kx = 0; kx < 3; kx++) {
      const int xx = x + kx - 1;
      if (xx < 0 || xx > 127) continue;
      acc += w[ky * 3 + kx] * Ap[yy * 128 + xx];
    }
  }
  Bq[idx] = acc;
}

// ---- per-channel 1/max(||row||,1e-12) over HW, rows 0..767 (q then k) ----
__global__ __launch_bounds__(256) void chan_norms(const float* __restrict__ Bq,
                                                  float* __restrict__ inv) {
  const int row = blockIdx.x;  // [0,768)
  const size_t base = (size_t)row * HW;
  const int tid = threadIdx.x;
  float s = 0.f;
  for (int p = tid; p < HW; p += 256) {
    float v = Bq[base + p];
    s += v * v;
  }
  for (int o = 32; o; o >>= 1) s += __shfl_xor(s, o);
  __shared__ float red[4];
  if ((tid & 63) == 0) red[tid >> 6] = s;
  __syncthreads();
  if (tid == 0) {
    float t = red[0] + red[1] + red[2] + red[3];
    inv[row] = 1.f / fmaxf(sqrtf(t), 1e-12f);
  }
}

// ---- channel-attn raw logits, chunked over HW, atomic accumulate ----
__global__ __launch_bounds__(256) void cattn_partial(const float* __restrict__ Bq,
                                                     float* __restrict__ raw) {
  __shared__ __align__(16) float qs[48][65];
  __shared__ __align__(16) float ks2[48][65];
  const int tid = threadIdx.x;
  const int chunk = blockIdx.x, h = blockIdx.y;
  const int p0 = chunk * 1024;
  const int tx = tid & 15, ty = tid >> 4;
  const size_t qbase = (size_t)(h * CH) * HW;
  const size_t kbase = (size_t)(CDIM + h * CH) * HW;
  float acc[3][3] = {};
  for (int pp = 0; pp < 1024; pp += 64) {
    for (int s = tid; s < 48 * 64; s += 256) {
      int cc = s >> 6, pl = s & 63;
      qs[cc][pl] = Bq[qbase + (size_t)cc * HW + p0 + pp + pl];
      ks2[cc][pl] = Bq[kbase + (size_t)cc * HW + p0 + pp + pl];
    }
    __syncthreads();
    for (int pl = 0; pl < 64; pl++) {
      float qv[3], kv[3];
#pragma unroll
      for (int ii = 0; ii < 3; ii++) qv[ii] = qs[ty * 3 + ii][pl];
#pragma unroll
      for (int jj = 0; jj < 3; jj++) kv[jj] = ks2[tx * 3 + jj][pl];
#pragma unroll
      for (int ii = 0; ii < 3; ii++)
#pragma unroll
        for (int jj = 0; jj < 3; jj++) acc[ii][jj] += qv[ii] * kv[jj];
    }
    __syncthreads();
  }
  float* rp = raw + (size_t)h * 2304;
#pragma unroll
  for (int ii = 0; ii < 3; ii++)
#pragma unroll
    for (int jj = 0; jj < 3; jj++)
      atomicAdd(&rp[(ty * 3 + ii) * 48 + tx * 3 + jj], acc[ii][jj]);
}

// ---- channel masked-softmax combine -> W48 ----
__global__ __launch_bounds__(64) void chan_softmax(
    const float* __restrict__ raw, const float* __restrict__ inv,
    const float* __restrict__ temp, const float* __restrict__ a1,
    const float* __restrict__ a2, const float* __restrict__ a3,
    const float* __restrict__ a4, float* __restrict__ W48) {
  const int blk = blockIdx.x;  // h*48 + i
  const int i = blk % 48;
  const int h = blk / 48;
  const int lane = threadIdx.x;
  const float t = temp[h];
  float a = -3.0e38f;
  if (lane < 48) {
    float r = raw[(size_t)blk * 48 + lane];
    a = t * inv[h * CH + i] * inv[CDIM + h * CH + lane] * r;
  }
  float m = a;
  for (int o = 32; o; o >>= 1) m = fmaxf(m, __shfl_xor(m, o));
  float e = (lane < 48) ? expf(a - m) : 0.f;
  int gt = 0;
  for (int j = 0; j < 48; j++) {
    float vj = __shfl(a, j);
    gt += (vj > a) ? 1 : 0;
  }
  const int ksel[4] = {24, 32, 36, 38};
  const float wts[4] = {a1[0], a2[0], a3[0], a4[0]};
  float coef = 0.f;
#pragma unroll
  for (int kk = 0; kk < 4; kk++) {
    float sel = (gt < ksel[kk]) ? e : 0.f;
    for (int o = 32; o; o >>= 1) sel += __shfl_xor(sel, o);
    if (gt < ksel[kk]) coef += wts[kk] / sel;
  }
  if (lane < 48) W48[(size_t)blk * 48 + lane] = e * coef;
}

// ---- channel out: Cbuf[h*48+i, p] = sum_j W48[h][i,j]*v[j,p] ----
__global__ __launch_bounds__(256) void cout_kernel(const float* __restrict__ W48,
                                                   const float* __restrict__ Bq,
                                                   float* __restrict__ Cbuf) {
  __shared__ __align__(16) float Wl[2304];
  const int tid = threadIdx.x;
  const int h = blockIdx.y;
  const float* wsrc = W48 + (size_t)h * 2304;
  for (int s = tid; s < 2304; s += 256) Wl[s] = wsrc[s];
  __syncthreads();
  const int p = blockIdx.x * 64 + (tid & 63);
  const int ig = tid >> 6;  // i in [ig*12, ig*12+12)
  const float* vbase = Bq + (size_t)(2 * CDIM + h * CH) * HW + p;
  float acc[12] = {};
  for (int j0 = 0; j0 < 48; j0 += 4) {
    float vj[4];
#pragma unroll
    for (int q = 0; q < 4; q++) vj[q] = vbase[(size_t)(j0 + q) * HW];
#pragma unroll
    for (int ii = 0; ii < 12; ii++) {
      const float4 w4 = *reinterpret_cast<const float4*>(&Wl[(ig * 12 + ii) * 48 + j0]);
      acc[ii] += w4.x * vj[0] + w4.y * vj[1] + w4.z * vj[2] + w4.w * vj[3];
    }
  }
  float* obase = Cbuf + (size_t)(h * CH + ig * 12) * HW + p;
#pragma unroll
  for (int ii = 0; ii < 12; ii++) obase[(size_t)ii * HW] = acc[ii];
}

// ---- window attention, one block per window, adds into Cbuf ----
__global__ __launch_bounds__(256) void spatial_kernel(
    const float* __restrict__ Bq, const float* __restrict__ temp,
    const float* __restrict__ a1, const float* __restrict__ a2,
    const float* __restrict__ a3, const float* __restrict__ a4,
    float* __restrict__ Cbuf) {
  __shared__ float qL[64 * 49];
  __shared__ float kL[64 * 49];
  __shared__ float vL[64 * 49];
  __shared__ float Pld[64 * 65];
  __shared__ float invqS[64], invkS[64];
  const int wid = blockIdx.x;  // head*256 + wy*16 + wx
  const int wx = wid & 15, wy = (wid >> 4) & 15;
  const int head = wid >> 8;
  const int tid = threadIdx.x;
  for (int s = tid; s < 3 * 3072; s += 256) {
    const int t = s / 3072;
    const int r = s % 3072;
    const int cc = r >> 6, n = r & 63;
    const int y = wy * 8 + (n >> 3), x = wx * 8 + (n & 7);
    const int chan = t * CDIM + head * CH + cc;
    float v = Bq[(size_t)chan * HW + y * 128 + x];
    float* dst = (t == 0) ? qL : (t == 1) ? kL : vL;
    dst[n * 49 + cc] = v;
  }
  __syncthreads();
  if (tid < 128) {
    const int t = tid >> 6, n = tid & 63;
    const float* src = t ? kL : qL;
    float s = 0.f;
    for (int cc = 0; cc < 48; cc++) {
      float v = src[n * 49 + cc];
      s += v * v;
    }
    float iv = 1.f / fmaxf(sqrtf(s), 1e-12f);
    if (t) invkS[n] = iv; else invqS[n] = iv;
  }
  __syncthreads();
  const float tscale = temp[wx & 7];
  const float wts[4] = {a1[0], a2[0], a3[0], a4[0]};
  const int ksel[4] = {32, 42, 48, 51};
  const int lane = tid & 63, w = tid >> 6;
  const float ik = invkS[lane];
  for (int g = 0; g < 4; g++) {
    const int n0 = w * 16 + g * 4;
    float accr[4] = {0.f, 0.f, 0.f, 0.f};
    for (int cc = 0; cc < 48; cc++) {
      const float kv = kL[lane * 49 + cc];
#pragma unroll
      for (int r = 0; r < 4; r++) accr[r] += qL[(n0 + r) * 49 + cc] * kv;
    }
#pragma unroll
    for (int r = 0; r < 4; r++) {
      const int n = n0 + r;
      const float a = accr[r] * invqS[n] * ik * tscale;
      float m = a;
      for (int o = 32; o; o >>= 1) m = fmaxf(m, __shfl_xor(m, o));
      const float e = expf(a - m);
      int gt = 0;
      for (int j = 0; j < 64; j++) {
        float vj = __shfl(a, j);
        gt += (vj > a) ? 1 : 0;
      }
      float coef = 0.f;
#pragma unroll
      for (int kk = 0; kk < 4; kk++) {
        float sel = (gt < ksel[kk]) ? e : 0.f;
        for (int o = 32; o; o >>= 1) sel += __shfl_xor(sel, o);
        if (gt < ksel[kk]) coef += wts[kk] / sel;
      }
      Pld[n * 65 + lane] = e * coef;
    }
  }
  __syncthreads();
  const int n = lane, cg = w;
  float acc[12] = {};
  for (int mm = 0; mm < 64; mm++) {
    const float pv = Pld[n * 65 + mm];
#pragma unroll
    for (int ci = 0; ci < 12; ci++) acc[ci] += pv * vL[mm * 49 + cg + ci * 4];
  }
  const int y_out = wy * 8 + (wx >> 1);
  const int x_out = (wx & 1) * 64 + n;
#pragma unroll
  for (int ci = 0; ci < 12; ci++) {
    const int cc = cg + ci * 4;
    const size_t idx = ((size_t)(head * CH + cc) * 128 + y_out) * 128 + x_out;
    Cbuf[idx] += acc[ci];
  }
}

// ---------------- launch ----------------
extern "C" void kernel_launch(void* const* d_in, const int* in_sizes, int n_in,
                              void* d_out, int out_size, void* d_ws, size_t ws_size,
                              hipStream_t stream) {
  const float* x = (const float*)d_in[0];
  const float* w_qkv = (const float*)d_in[1];
  const float* w_dw = (const float*)d_in[2];
  const float* w_proj = (const float*)d_in[3];
  const float* temp = (const float*)d_in[4];
  const float* a1 = (const float*)d_in[5];
  const float* a2 = (const float*)d_in[6];
  const float* a3 = (const float*)d_in[7];
  const float* a4 = (const float*)d_in[8];
  float* out = (float*)d_out;

  // Workspace layout (bytes):
  //   [0,      73728)    cattn_raw f32 (8*48*48)
  //   [73728, 147456)    W48       f32
  //   [147456,150528)    inv       f32 (768)
  //   [150784,75648256)  Bq        f32 (1152*16384)  — also proj temp output
  // Peak 75.6 MB. d_out[b] region used as conv1 scratch (At) and Cbuf.
  char* ws = (char*)d_ws;
  float* cattn_raw = (float*)ws;
  float* W48 = (float*)(ws + 73728);
  float* inv = (float*)(ws + 147456);
  float* Bq = (float*)(ws + 150784);

  for (int b = 0; b < 2; b++) {
    const float* xb = x + (size_t)b * CDIM * HW;
    float* ob = out + (size_t)b * CDIM * HW;  // scratch (At/Cbuf) then final

    zero_f32<<<(NHEADS * 48 * 48 + 255) / 256, 256, 0, stream>>>(cattn_raw, NHEADS * 48 * 48);

    for (int t = 0; t < 3; t++) {
      gemm1x1_f32<<<dim3(HW / 64, CDIM / 64), 256, 0, stream>>>(
          w_qkv + (size_t)t * CDIM * CDIM, xb, ob, CDIM);
      dwconv3<<<(CDIM * HW) / 256, 256, 0, stream>>>(
          ob, w_dw + (size_t)t * CDIM * 9, Bq + (size_t)t * CDIM * HW);
    }

    chan_norms<<<2 * CDIM, 256, 0, stream>>>(Bq, inv);
    cattn_partial<<<dim3(16, NHEADS), 256, 0, stream>>>(Bq, cattn_raw);
    chan_softmax<<<NHEADS * 48, 64, 0, stream>>>(cattn_raw, inv, temp, a1, a2, a3, a4, W48);
    cout_kernel<<<dim3(HW / 64, NHEADS), 256, 0, stream>>>(W48, Bq, ob);
    spatial_kernel<<<NHEADS * 256, 256, 0, stream>>>(Bq, temp, a1, a2, a3, a4, ob);
    // proj: read Cbuf(=ob), write into dead Bq region, then copy back to ob.
    gemm1x1_f32<<<dim3(HW / 64, CDIM / 64), 256, 0, stream>>>(w_proj, ob, Bq, CDIM);
    copy_f32<<<(CDIM * HW / 4 + 255) / 256, 256, 0, stream>>>(Bq, ob, CDIM * HW / 4);
  }

  (void)in_sizes; (void)n_in; (void)out_size; (void)ws_size;
}

// Round 5
// 1495.318 us; speedup vs baseline: 1.1894x; 1.1894x over previous
//
#include <hip/hip_runtime.h>

// TKMDAttention on MI355X — round 5: fp32 pipeline (round-4 PASS baseline),
// + high-ILP 64x128 GEMM (4x8 register block) and spatial_kernel occupancy fix
// (LDS overlay 54.8->42.2 KB => 3 blocks/CU) + bitonic-sort top-k softmax.
// Shapes: b=2, C=384, H=W=128, heads=8, ch=48, crop=8, N=64.
// windowstoimg mapping: token n of window (wy,wx) -> y = wy*8+(wx>>1), x = (wx&1)*64+n.
// top-k rule (tie-exact): keep i for k iff a_i >= sorted_asc[64-k] (== ref "a >= kth").

#define HW 16384
#define CDIM 384
#define NHEADS 8
#define CH 48

// ---------------- zero ----------------
__global__ void zero_f32(float* p, int n) {
  int i = blockIdx.x * 256 + threadIdx.x;
  if (i < n) p[i] = 0.f;
}

// ---------------- copy ----------------
__global__ __launch_bounds__(256) void copy_f32(const float* __restrict__ src,
                                                float* __restrict__ dst, int n4) {
  int i = blockIdx.x * 256 + threadIdx.x;
  if (i < n4) reinterpret_cast<float4*>(dst)[i] = reinterpret_cast<const float4*>(src)[i];
}

// ---- 1x1 conv as GEMM: Out[oc,p] = sum_ic W[oc,ic]*X[ic,p] (single batch) ----
// Tile: 64 oc x 128 p, BK=16; per-thread 4 oc x 8 p (two 4-wide p halves).
__global__ __launch_bounds__(256) void gemm1x1_f32(const float* __restrict__ Wt,
                                                   const float* __restrict__ X,
                                                   float* __restrict__ Out, int K) {
  __shared__ __align__(16) float Xs[16][128];
  __shared__ __align__(16) float Ws[16][68];
  const int tid = threadIdx.x;
  const int tx = tid & 15, ty = tid >> 4;  // p-group (16), oc-group (16)
  const int p0 = blockIdx.x * 128;
  const int oc0 = blockIdx.y * 64;
  // global-load mapping
  const int xr1 = tid >> 5, xc1 = (tid & 31) * 4;          // X: rows 0..7
  const int wocl = tid >> 2, wkq = (tid & 3) * 4;          // W: 64 oc x 4 k-quads
  float acc[4][8] = {};
  for (int k0 = 0; k0 < K; k0 += 16) {
    const float4 xv1 = *reinterpret_cast<const float4*>(&X[(size_t)(k0 + xr1) * HW + p0 + xc1]);
    const float4 xv2 = *reinterpret_cast<const float4*>(&X[(size_t)(k0 + 8 + xr1) * HW + p0 + xc1]);
    const float4 wv4 = *reinterpret_cast<const float4*>(&Wt[(size_t)(oc0 + wocl) * K + k0 + wkq]);
    *reinterpret_cast<float4*>(&Xs[xr1][xc1]) = xv1;
    *reinterpret_cast<float4*>(&Xs[8 + xr1][xc1]) = xv2;
    Ws[wkq + 0][wocl] = wv4.x;
    Ws[wkq + 1][wocl] = wv4.y;
    Ws[wkq + 2][wocl] = wv4.z;
    Ws[wkq + 3][wocl] = wv4.w;
    __syncthreads();
#pragma unroll
    for (int kk = 0; kk < 16; kk++) {
      const float4 xa = *reinterpret_cast<const float4*>(&Xs[kk][tx * 4]);
      const float4 xb = *reinterpret_cast<const float4*>(&Xs[kk][64 + tx * 4]);
      const float4 wv = *reinterpret_cast<const float4*>(&Ws[kk][ty * 4]);
      const float xr[8] = {xa.x, xa.y, xa.z, xa.w, xb.x, xb.y, xb.z, xb.w};
      const float wr[4] = {wv.x, wv.y, wv.z, wv.w};
#pragma unroll
      for (int i = 0; i < 4; i++)
#pragma unroll
        for (int j = 0; j < 8; j++) acc[i][j] += wr[i] * xr[j];
    }
    __syncthreads();
  }
#pragma unroll
  for (int i = 0; i < 4; i++) {
    const size_t base = (size_t)(oc0 + ty * 4 + i) * HW + p0;
    float4 o1 = {acc[i][0], acc[i][1], acc[i][2], acc[i][3]};
    float4 o2 = {acc[i][4], acc[i][5], acc[i][6], acc[i][7]};
    *reinterpret_cast<float4*>(&Out[base + tx * 4]) = o1;
    *reinterpret_cast<float4*>(&Out[base + 64 + tx * 4]) = o2;
  }
}

// ---- depthwise 3x3 pad1, 384 channels (one qkv third) ----
__global__ __launch_bounds__(256) void dwconv3(const float* __restrict__ A,
                                               const float* __restrict__ wdw,
                                               float* __restrict__ Bq) {
  const int idx = blockIdx.x * 256 + threadIdx.x;  // flat over (ch<384, y, x)
  const int x = idx & 127;
  const int y = (idx >> 7) & 127;
  const int ch = idx >> 14;
  float w[9];
#pragma unroll
  for (int t = 0; t < 9; t++) w[t] = wdw[ch * 9 + t];
  const float* Ap = A + (size_t)ch * HW;
  float acc = 0.f;
#pragma unroll
  for (int ky = 0; ky < 3; ky++) {
    const int yy = y + ky - 1;
    if (yy < 0 || yy > 127) continue;
#pragma unroll
    for (int kx = 0; kx < 3; kx++) {
      const int xx = x + kx - 1;
      if (xx < 0 || xx > 127) continue;
      acc += w[ky * 3 + kx] * Ap[yy * 128 + xx];
    }
  }
  Bq[idx] = acc;
}

// ---- per-channel 1/max(||row||,1e-12) over HW, rows 0..767 (q then k) ----
__global__ __launch_bounds__(256) void chan_norms(const float* __restrict__ Bq,
                                                  float* __restrict__ inv) {
  const int row = blockIdx.x;  // [0,768)
  const size_t base = (size_t)row * HW;
  const int tid = threadIdx.x;
  float s = 0.f;
  for (int p = tid; p < HW; p += 256) {
    float v = Bq[base + p];
    s += v * v;
  }
  for (int o = 32; o; o >>= 1) s += __shfl_xor(s, o);
  __shared__ float red[4];
  if ((tid & 63) == 0) red[tid >> 6] = s;
  __syncthreads();
  if (tid == 0) {
    float t = red[0] + red[1] + red[2] + red[3];
    inv[row] = 1.f / fmaxf(sqrtf(t), 1e-12f);
  }
}

// ---- channel-attn raw logits, chunked over HW, atomic accumulate ----
__global__ __launch_bounds__(256) void cattn_partial(const float* __restrict__ Bq,
                                                     float* __restrict__ raw) {
  __shared__ __align__(16) float qs[48][65];
  __shared__ __align__(16) float ks2[48][65];
  const int tid = threadIdx.x;
  const int chunk = blockIdx.x, h = blockIdx.y;
  const int p0 = chunk * 1024;
  const int tx = tid & 15, ty = tid >> 4;
  const size_t qbase = (size_t)(h * CH) * HW;
  const size_t kbase = (size_t)(CDIM + h * CH) * HW;
  float acc[3][3] = {};
  for (int pp = 0; pp < 1024; pp += 64) {
    for (int s = tid; s < 48 * 64; s += 256) {
      int cc = s >> 6, pl = s & 63;
      qs[cc][pl] = Bq[qbase + (size_t)cc * HW + p0 + pp + pl];
      ks2[cc][pl] = Bq[kbase + (size_t)cc * HW + p0 + pp + pl];
    }
    __syncthreads();
    for (int pl = 0; pl < 64; pl++) {
      float qv[3], kv[3];
#pragma unroll
      for (int ii = 0; ii < 3; ii++) qv[ii] = qs[ty * 3 + ii][pl];
#pragma unroll
      for (int jj = 0; jj < 3; jj++) kv[jj] = ks2[tx * 3 + jj][pl];
#pragma unroll
      for (int ii = 0; ii < 3; ii++)
#pragma unroll
        for (int jj = 0; jj < 3; jj++) acc[ii][jj] += qv[ii] * kv[jj];
    }
    __syncthreads();
  }
  float* rp = raw + (size_t)h * 2304;
#pragma unroll
  for (int ii = 0; ii < 3; ii++)
#pragma unroll
    for (int jj = 0; jj < 3; jj++)
      atomicAdd(&rp[(ty * 3 + ii) * 48 + tx * 3 + jj], acc[ii][jj]);
}

// ---- channel masked-softmax combine -> W48 ----
__global__ __launch_bounds__(64) void chan_softmax(
    const float* __restrict__ raw, const float* __restrict__ inv,
    const float* __restrict__ temp, const float* __restrict__ a1,
    const float* __restrict__ a2, const float* __restrict__ a3,
    const float* __restrict__ a4, float* __restrict__ W48) {
  const int blk = blockIdx.x;  // h*48 + i
  const int i = blk % 48;
  const int h = blk / 48;
  const int lane = threadIdx.x;
  const float t = temp[h];
  float a = -3.0e38f;
  if (lane < 48) {
    float r = raw[(size_t)blk * 48 + lane];
    a = t * inv[h * CH + i] * inv[CDIM + h * CH + lane] * r;
  }
  float m = a;
  for (int o = 32; o; o >>= 1) m = fmaxf(m, __shfl_xor(m, o));
  float e = (lane < 48) ? expf(a - m) : 0.f;
  int gt = 0;
  for (int j = 0; j < 48; j++) {
    float vj = __shfl(a, j);
    gt += (vj > a) ? 1 : 0;
  }
  const int ksel[4] = {24, 32, 36, 38};
  const float wts[4] = {a1[0], a2[0], a3[0], a4[0]};
  float coef = 0.f;
#pragma unroll
  for (int kk = 0; kk < 4; kk++) {
    float sel = (gt < ksel[kk]) ? e : 0.f;
    for (int o = 32; o; o >>= 1) sel += __shfl_xor(sel, o);
    if (gt < ksel[kk]) coef += wts[kk] / sel;
  }
  if (lane < 48) W48[(size_t)blk * 48 + lane] = e * coef;
}

// ---- channel out: Cbuf[h*48+i, p] = sum_j W48[h][i,j]*v[j,p] ----
__global__ __launch_bounds__(256) void cout_kernel(const float* __restrict__ W48,
                                                   const float* __restrict__ Bq,
                                                   float* __restrict__ Cbuf) {
  __shared__ __align__(16) float Wl[2304];
  const int tid = threadIdx.x;
  const int h = blockIdx.y;
  const float* wsrc = W48 + (size_t)h * 2304;
  for (int s = tid; s < 2304; s += 256) Wl[s] = wsrc[s];
  __syncthreads();
  const int p = blockIdx.x * 64 + (tid & 63);
  const int ig = tid >> 6;  // i in [ig*12, ig*12+12)
  const float* vbase = Bq + (size_t)(2 * CDIM + h * CH) * HW + p;
  float acc[12] = {};
  for (int j0 = 0; j0 < 48; j0 += 4) {
    float vj[4];
#pragma unroll
    for (int q = 0; q < 4; q++) vj[q] = vbase[(size_t)(j0 + q) * HW];
#pragma unroll
    for (int ii = 0; ii < 12; ii++) {
      const float4 w4 = *reinterpret_cast<const float4*>(&Wl[(ig * 12 + ii) * 48 + j0]);
      acc[ii] += w4.x * vj[0] + w4.y * vj[1] + w4.z * vj[2] + w4.w * vj[3];
    }
  }
  float* obase = Cbuf + (size_t)(h * CH + ig * 12) * HW + p;
#pragma unroll
  for (int ii = 0; ii < 12; ii++) obase[(size_t)ii * HW] = acc[ii];
}

// ---- window attention, one block per window, adds into Cbuf ----
// LDS overlay: qvL holds q in phase 1 (QK^T), then v in phase 2 (PV).
__global__ __launch_bounds__(256) void spatial_kernel(
    const float* __restrict__ Bq, const float* __restrict__ temp,
    const float* __restrict__ a1, const float* __restrict__ a2,
    const float* __restrict__ a3, const float* __restrict__ a4,
    float* __restrict__ Cbuf) {
  __shared__ float kL[64 * 49];
  __shared__ float qvL[64 * 49];
  __shared__ float Pld[64 * 65];
  __shared__ float invqS[64], invkS[64];
  const int wid = blockIdx.x;  // head*256 + wy*16 + wx
  const int wx = wid & 15, wy = (wid >> 4) & 15;
  const int head = wid >> 8;
  const int tid = threadIdx.x;
  // phase 1: load q,k
  for (int s = tid; s < 2 * 3072; s += 256) {
    const int t = s / 3072;  // 0=q, 1=k
    const int r = s % 3072;
    const int cc = r >> 6, n = r & 63;
    const int y = wy * 8 + (n >> 3), x = wx * 8 + (n & 7);
    const int chan = t * CDIM + head * CH + cc;
    (t ? kL : qvL)[n * 49 + cc] = Bq[(size_t)chan * HW + y * 128 + x];
  }
  __syncthreads();
  if (tid < 128) {
    const int t = tid >> 6, n = tid & 63;
    const float* src = t ? kL : qvL;
    float s = 0.f;
    for (int cc = 0; cc < 48; cc++) {
      float v = src[n * 49 + cc];
      s += v * v;
    }
    float iv = 1.f / fmaxf(sqrtf(s), 1e-12f);
    if (t) invkS[n] = iv; else invqS[n] = iv;
  }
  __syncthreads();
  const float tscale = temp[wx & 7];
  const float wts[4] = {a1[0], a2[0], a3[0], a4[0]};
  const int ksel[4] = {32, 42, 48, 51};
  const int lane = tid & 63, w = tid >> 6;
  const float ik = invkS[lane];
  for (int g = 0; g < 4; g++) {
    const int n0 = w * 16 + g * 4;
    float accr[4] = {0.f, 0.f, 0.f, 0.f};
    for (int cc = 0; cc < 48; cc++) {
      const float kv = kL[lane * 49 + cc];
#pragma unroll
      for (int r = 0; r < 4; r++) accr[r] += qvL[(n0 + r) * 49 + cc] * kv;
    }
#pragma unroll
    for (int r = 0; r < 4; r++) {
      const int n = n0 + r;
      const float a = accr[r] * invqS[n] * ik * tscale;
      // bitonic sort ascending across 64 lanes (copy of a)
      float s = a;
#pragma unroll
      for (int k = 2; k <= 64; k <<= 1) {
#pragma unroll
        for (int j = k >> 1; j > 0; j >>= 1) {
          const float o = __shfl_xor(s, j);
          const bool up = ((lane & k) == 0);
          const bool lower = ((lane & j) == 0);
          const float mn = fminf(s, o), mx = fmaxf(s, o);
          s = (lower == up) ? mn : mx;
        }
      }
      const float m = __shfl(s, 63);  // global max (always kept)
      const float e = expf(a - m);
      float coef = 0.f;
#pragma unroll
      for (int kk = 0; kk < 4; kk++) {
        const float tk = __shfl(s, 64 - ksel[kk]);  // k-th largest (tie-incl.)
        const bool keep = (a >= tk);
        float sel = keep ? e : 0.f;
        for (int o = 32; o; o >>= 1) sel += __shfl_xor(sel, o);
        if (keep) coef += wts[kk] / sel;
      }
      Pld[n * 65 + lane] = e * coef;
    }
  }
  __syncthreads();
  // phase 2: load v over q (q is dead)
  for (int s = tid; s < 3072; s += 256) {
    const int cc = s >> 6, n = s & 63;
    const int y = wy * 8 + (n >> 3), x = wx * 8 + (n & 7);
    const int chan = 2 * CDIM + head * CH + cc;
    qvL[n * 49 + cc] = Bq[(size_t)chan * HW + y * 128 + x];
  }
  __syncthreads();
  const int n = lane, cg = w;
  float acc[12] = {};
  for (int mm = 0; mm < 64; mm++) {
    const float pv = Pld[n * 65 + mm];
#pragma unroll
    for (int ci = 0; ci < 12; ci++) acc[ci] += pv * qvL[mm * 49 + cg + ci * 4];
  }
  const int y_out = wy * 8 + (wx >> 1);
  const int x_out = (wx & 1) * 64 + n;
#pragma unroll
  for (int ci = 0; ci < 12; ci++) {
    const int cc = cg + ci * 4;
    const size_t idx = ((size_t)(head * CH + cc) * 128 + y_out) * 128 + x_out;
    Cbuf[idx] += acc[ci];
  }
}

// ---------------- launch ----------------
extern "C" void kernel_launch(void* const* d_in, const int* in_sizes, int n_in,
                              void* d_out, int out_size, void* d_ws, size_t ws_size,
                              hipStream_t stream) {
  const float* x = (const float*)d_in[0];
  const float* w_qkv = (const float*)d_in[1];
  const float* w_dw = (const float*)d_in[2];
  const float* w_proj = (const float*)d_in[3];
  const float* temp = (const float*)d_in[4];
  const float* a1 = (const float*)d_in[5];
  const float* a2 = (const float*)d_in[6];
  const float* a3 = (const float*)d_in[7];
  const float* a4 = (const float*)d_in[8];
  float* out = (float*)d_out;

  // Workspace layout (bytes):
  //   [0,      73728)    cattn_raw f32 (8*48*48)
  //   [73728, 147456)    W48       f32
  //   [147456,150528)    inv       f32 (768)
  //   [150784,75648256)  Bq        f32 (1152*16384)  — also proj temp output
  // Peak 75.6 MB. d_out[b] region used as conv1 scratch (At) and Cbuf.
  char* ws = (char*)d_ws;
  float* cattn_raw = (float*)ws;
  float* W48 = (float*)(ws + 73728);
  float* inv = (float*)(ws + 147456);
  float* Bq = (float*)(ws + 150784);

  for (int b = 0; b < 2; b++) {
    const float* xb = x + (size_t)b * CDIM * HW;
    float* ob = out + (size_t)b * CDIM * HW;  // scratch (At/Cbuf) then final

    zero_f32<<<(NHEADS * 48 * 48 + 255) / 256, 256, 0, stream>>>(cattn_raw, NHEADS * 48 * 48);

    for (int t = 0; t < 3; t++) {
      gemm1x1_f32<<<dim3(HW / 128, CDIM / 64), 256, 0, stream>>>(
          w_qkv + (size_t)t * CDIM * CDIM, xb, ob, CDIM);
      dwconv3<<<(CDIM * HW) / 256, 256, 0, stream>>>(
          ob, w_dw + (size_t)t * CDIM * 9, Bq + (size_t)t * CDIM * HW);
    }

    chan_norms<<<2 * CDIM, 256, 0, stream>>>(Bq, inv);
    cattn_partial<<<dim3(16, NHEADS), 256, 0, stream>>>(Bq, cattn_raw);
    chan_softmax<<<NHEADS * 48, 64, 0, stream>>>(cattn_raw, inv, temp, a1, a2, a3, a4, W48);
    cout_kernel<<<dim3(HW / 64, NHEADS), 256, 0, stream>>>(W48, Bq, ob);
    spatial_kernel<<<NHEADS * 256, 256, 0, stream>>>(Bq, temp, a1, a2, a3, a4, ob);
    // proj: read Cbuf(=ob), write into dead Bq region, then copy back to ob.
    gemm1x1_f32<<<dim3(HW / 128, CDIM / 64), 256, 0, stream>>>(w_proj, ob, Bq, CDIM);
    copy_f32<<<(CDIM * HW / 4 + 255) / 256, 256, 0, stream>>>(Bq, ob, CDIM * HW / 4);
  }

  (void)in_sizes; (void)n_in; (void)out_size; (void)ws_size;
}